// Round 2
// baseline (564.378 us; speedup 1.0000x reference)
//
#include <hip/hip_runtime.h>
#include <hip/hip_bf16.h>
#include <stdint.h>

// Problem constants (IMAGE_SIZES is compile-time constant in the reference)
#define K_DIM 4096          // D * MERGE^2
#define N_DIM 1024          // D
#define M_TOT 11955         // total merged blocks

#define BM 128
#define BN 128
#define BK 64
#define SA 72               // padded lA row stride (elts): 144 B = 9*16 B -> conflict-free

// Per-image tables: h = H/14, w = W/14; wm = w/2
__constant__ int c_wm[6]     = {44, 55, 45, 55, 32, 55};
__constant__ int c_w[6]      = {88, 110, 90, 110, 64, 110};
__constant__ int c_tokoff[6] = {0, 9680, 18480, 24240, 36340, 42100};
__constant__ int c_blkoff[6] = {0, 2420, 4620, 6060, 9085, 10525};

typedef __attribute__((ext_vector_type(8))) short bf16x8;
typedef __attribute__((ext_vector_type(4))) float f32x4;

// ---------------------------------------------------------------------------
// Weight fp32 -> bf16 (1024 x 4096 row-major, K contiguous). ~24 MB traffic.
// ---------------------------------------------------------------------------
__global__ __launch_bounds__(256) void wcvt(
    const float* __restrict__ src, __hip_bfloat16* __restrict__ dst)
{
    const int idx = blockIdx.x * 256 + threadIdx.x;
    const float4* s = (const float4*)src + (size_t)idx * 2;
    float4 a = s[0], b = s[1];
    union { __hip_bfloat16 h[8]; uint4 u; } pk;
    pk.h[0] = __float2bfloat16(a.x); pk.h[1] = __float2bfloat16(a.y);
    pk.h[2] = __float2bfloat16(a.z); pk.h[3] = __float2bfloat16(a.w);
    pk.h[4] = __float2bfloat16(b.x); pk.h[5] = __float2bfloat16(b.y);
    pk.h[6] = __float2bfloat16(b.z); pk.h[7] = __float2bfloat16(b.w);
    *((uint4*)dst + idx) = pk.u;
}

// ---------------------------------------------------------------------------
// Fused: A = on-the-fly 2x2 patch-merge + fp32->bf16 of feat; B = bf16 weight
// staged via global_load_lds (XOR source swizzle for conflict-free reads).
// C[m,n] = sum_k A[m,k] * W[n,k].  128x128 tile, BK=64, 4 waves (2x2 of 64x64),
// 16x16x32 bf16 MFMA, 2 k-steps per tile.
// ---------------------------------------------------------------------------
__global__ __launch_bounds__(256) void gemm_fused(
    const float* __restrict__ feat,
    const __hip_bfloat16* __restrict__ Bw,
    float* __restrict__ C)
{
    __shared__ __align__(16) __hip_bfloat16 lA[BM * SA]; // 18 KB
    __shared__ __align__(16) __hip_bfloat16 lB[BN * BK]; // 16 KB

    const int tid  = threadIdx.x;
    const int lane = tid & 63;
    const int wave = tid >> 6;
    const int m0 = blockIdx.y * BM;
    const int n0 = blockIdx.x * BN;
    const int wm = (wave >> 1) * 64;
    const int wn = (wave & 1) * 64;
    const int al = lane & 15;
    const int q  = lane >> 4;

    // ---- A gather setup: thread pair (tid, tid^1) covers one merged row.
    // arow = tid>>1, ksel = (tid&1)*32 elements within the BK=64 tile.
    const int arow = tid >> 1;
    const int ksel = (tid & 1) * 32;
    int gm = m0 + arow; if (gm > M_TOT - 1) gm = M_TOT - 1; // clamp edge tile
    int img = 0;
#pragma unroll
    for (int t = 1; t < 6; ++t) if (gm >= c_blkoff[t]) img = t;
    const int bi = gm - c_blkoff[img];
    const int wmrg = c_wm[img];
    const int gi = bi / wmrg;
    const int gj = bi - gi * wmrg;
    const int w  = c_w[img];
    // token (2i+kh, 2j+kw), feature d; merged k = d*4 + kh*2 + kw
    const size_t b00 = ((size_t)c_tokoff[img] + (size_t)(2 * gi) * w + 2 * gj) * (size_t)N_DIM;
    const float* s00 = feat + b00;
    const float* s01 = s00 + N_DIM;             // kw=1
    const float* s10 = s00 + (size_t)w * N_DIM; // kh=1
    const float* s11 = s10 + N_DIM;
    __hip_bfloat16* lA_dst = lA + arow * SA + ksel;

    // ---- B staging src: 4 chunks/thread; LDS pos p = c&7 holds global chunk
    // g = p ^ (row&7) so fragment reads walk all 8 bank groups.
    const __hip_bfloat16* bsrc[4];
#pragma unroll
    for (int j = 0; j < 4; ++j) {
        const int c = tid + j * 256;
        const int row = c >> 3;
        const int p = c & 7;
        const int g = p ^ (row & 7);
        bsrc[j] = Bw + (size_t)(n0 + row) * K_DIM + g * 8;
    }

    f32x4 acc[4][4];
#pragma unroll
    for (int i = 0; i < 4; ++i)
#pragma unroll
        for (int j = 0; j < 4; ++j)
            acc[i][j] = (f32x4){0.f, 0.f, 0.f, 0.f};

    union f8 { float4 v[2]; float f[8]; };

    for (int kt = 0; kt < K_DIM; kt += BK) {
        // A global loads (fp32): issue before barrier so latency overlaps
        // the previous tile's MFMAs on other waves.
        const int d0 = (kt + ksel) >> 2;   // 8 consecutive d per thread
        f8 r0, r1, r2, r3;
        r0.v[0] = *(const float4*)(s00 + d0); r0.v[1] = *(const float4*)(s00 + d0 + 4);
        r1.v[0] = *(const float4*)(s01 + d0); r1.v[1] = *(const float4*)(s01 + d0 + 4);
        r2.v[0] = *(const float4*)(s10 + d0); r2.v[1] = *(const float4*)(s10 + d0 + 4);
        r3.v[0] = *(const float4*)(s11 + d0); r3.v[1] = *(const float4*)(s11 + d0 + 4);

        __syncthreads();   // previous tile's LDS reads complete

        // B: async DMA into LDS (wave-uniform base + lane*16)
#pragma unroll
        for (int j = 0; j < 4; ++j)
            __builtin_amdgcn_global_load_lds(
                (const __attribute__((address_space(1))) void*)(bsrc[j] + kt),
                (__attribute__((address_space(3))) void*)(lB + (tid + j * 256) * 8),
                16, 0, 0);

        // A: convert + interleave (d,kh,kw channel-major) + ds_write_b128
#pragma unroll
        for (int j = 0; j < 4; ++j) {
            const int dd = 2 * j;
            union { __hip_bfloat162 h2[4]; uint4 u; } pk;
            pk.h2[0] = __float22bfloat162_rn(make_float2(r0.f[dd],     r1.f[dd]));
            pk.h2[1] = __float22bfloat162_rn(make_float2(r2.f[dd],     r3.f[dd]));
            pk.h2[2] = __float22bfloat162_rn(make_float2(r0.f[dd + 1], r1.f[dd + 1]));
            pk.h2[3] = __float22bfloat162_rn(make_float2(r2.f[dd + 1], r3.f[dd + 1]));
            *(uint4*)(lA_dst + j * 8) = pk.u;
        }
        __syncthreads();   // staging (DMA + ds_write) complete

        // compute: 2 k-steps of 16x16x32
#pragma unroll
        for (int ks = 0; ks < 2; ++ks) {
            bf16x8 af[4], bfr[4];
#pragma unroll
            for (int mi = 0; mi < 4; ++mi)
                af[mi] = *(const bf16x8*)(lA + (wm + mi * 16 + al) * SA + ks * 32 + q * 8);
#pragma unroll
            for (int ni = 0; ni < 4; ++ni) {
                const int row = wn + ni * 16 + al;
                const int p = (ks * 4 + q) ^ (row & 7);
                bfr[ni] = *(const bf16x8*)(lB + row * BK + p * 8);
            }
#pragma unroll
            for (int mi = 0; mi < 4; ++mi)
#pragma unroll
                for (int ni = 0; ni < 4; ++ni)
                    acc[mi][ni] = __builtin_amdgcn_mfma_f32_16x16x32_bf16(
                        af[mi], bfr[ni], acc[mi][ni], 0, 0, 0);
        }
    }

    // C/D layout: col = lane&15, row = (lane>>4)*4 + reg
#pragma unroll
    for (int mi = 0; mi < 4; ++mi) {
        const int row = m0 + wm + mi * 16 + q * 4;
#pragma unroll
        for (int ni = 0; ni < 4; ++ni) {
            const int col = n0 + wn + ni * 16 + al;
            float* cp = C + (size_t)row * N_DIM + col;
#pragma unroll
            for (int rg = 0; rg < 4; ++rg) {
                if (row + rg < M_TOT) cp[(size_t)rg * N_DIM] = acc[mi][ni][rg];
            }
        }
    }
}

extern "C" void kernel_launch(void* const* d_in, const int* in_sizes, int n_in,
                              void* d_out, int out_size, void* d_ws, size_t ws_size,
                              hipStream_t stream)
{
    const float* feat = (const float*)d_in[0];
    const float* wgt  = (const float*)d_in[1];
    float* out = (float*)d_out;

    __hip_bfloat16* wbf = (__hip_bfloat16*)d_ws;   // 8 MB

    wcvt<<<(N_DIM * K_DIM / 8) / 256, 256, 0, stream>>>(wgt, wbf);

    dim3 grid(N_DIM / BN, (M_TOT + BM - 1) / BM);  // (8, 94)
    gemm_fused<<<grid, 256, 0, stream>>>(feat, wbf, out);
}

// Round 3
// 437.172 us; speedup vs baseline: 1.2910x; 1.2910x over previous
//
#include <hip/hip_runtime.h>
#include <hip/hip_bf16.h>
#include <stdint.h>

// Problem constants (IMAGE_SIZES is compile-time constant in the reference)
#define K_DIM 4096          // D * MERGE^2
#define N_DIM 1024          // D
#define M_TOT 11955         // total merged blocks

#define BM 128
#define BN 128
#define BK 64

// Per-image tables: h = H/14, w = W/14; wm = w/2
__constant__ int c_wm[6]     = {44, 55, 45, 55, 32, 55};
__constant__ int c_w[6]      = {88, 110, 90, 110, 64, 110};
__constant__ int c_tokoff[6] = {0, 9680, 18480, 24240, 36340, 42100};
__constant__ int c_blkoff[6] = {0, 2420, 4620, 6060, 9085, 10525};

typedef __attribute__((ext_vector_type(8))) short bf16x8;
typedef __attribute__((ext_vector_type(4))) float f32x4;

// ---------------------------------------------------------------------------
// Pass 1a: feat fp32 -> bf16, pure streaming (no gather). 196 MB r + 98 MB w.
// 47820*1024 = 48967680 elts = 6120960 x8-chunks = 23910 blocks x 256 thr.
// ---------------------------------------------------------------------------
__global__ __launch_bounds__(256) void cvt_feat(
    const float* __restrict__ src, __hip_bfloat16* __restrict__ dst)
{
    const size_t idx = (size_t)blockIdx.x * 256 + threadIdx.x;
    const float4* s = (const float4*)src + idx * 2;
    float4 a = s[0], b = s[1];
    union { __hip_bfloat16 h[8]; uint4 u; } pk;
    pk.h[0] = __float2bfloat16(a.x); pk.h[1] = __float2bfloat16(a.y);
    pk.h[2] = __float2bfloat16(a.z); pk.h[3] = __float2bfloat16(a.w);
    pk.h[4] = __float2bfloat16(b.x); pk.h[5] = __float2bfloat16(b.y);
    pk.h[6] = __float2bfloat16(b.z); pk.h[7] = __float2bfloat16(b.w);
    *((uint4*)dst + idx) = pk.u;
}

// ---------------------------------------------------------------------------
// Pass 1b: weight fp32 -> bf16 with K-permutation k' = seg*1024 + d where
// original k = 4d + seg (seg = 2*kh + kw). Wp[n, seg*1024+d] = W[n, 4d+seg].
// Thread handles k = 8t..8t+7 (d = 2t, 2t+1 for all 4 segs).
// ---------------------------------------------------------------------------
__global__ __launch_bounds__(256) void wperm_cvt(
    const float* __restrict__ src, __hip_bfloat16* __restrict__ dst)
{
    const int n = blockIdx.x >> 1;
    const int t = (blockIdx.x & 1) * 256 + threadIdx.x;   // 0..511
    const float* row = src + (size_t)n * K_DIM + t * 8;
    float4 a = *(const float4*)row;        // k = 8t..8t+3  (d = 2t)
    float4 b = *(const float4*)(row + 4);  // k = 8t+4..8t+7 (d = 2t+1)
    const float va[8] = {a.x, a.y, a.z, a.w, b.x, b.y, b.z, b.w};
    __hip_bfloat16* drow = dst + (size_t)n * K_DIM + 2 * t;
#pragma unroll
    for (int seg = 0; seg < 4; ++seg) {
        __hip_bfloat162 h = __float22bfloat162_rn(
            make_float2(va[seg], va[4 + seg]));
        *(__hip_bfloat162*)(drow + seg * 1024) = h;
    }
}

// ---------------------------------------------------------------------------
// Pass 2: bf16 GEMM over permuted K. C[m,n] = sum_k' A'[m,k'] Wp[n,k'] where
// A'[m, seg*1024+d] = featbf[tok(m,seg)*1024 + d] — contiguous per segment,
// staged with global_load_lds width-16. XOR chunk swizzle (g = p ^ (row&7))
// makes fragment ds_read_b128 conflict-free (2-way only). 128x128 tile,
// BK=64, 4 waves (2x2 of 64x64), 16x16x32 bf16 MFMA, 2 k-steps/tile.
// ---------------------------------------------------------------------------
__global__ __launch_bounds__(256) void gemm_bt(
    const __hip_bfloat16* __restrict__ A,   // featbf [47820 x 1024]
    const __hip_bfloat16* __restrict__ Wp,  // permuted weight [1024 x 4096]
    float* __restrict__ C)
{
    __shared__ __align__(16) __hip_bfloat16 lA[BM * BK]; // 16 KB
    __shared__ __align__(16) __hip_bfloat16 lB[BN * BK]; // 16 KB

    const int tid  = threadIdx.x;
    const int lane = tid & 63;
    const int wave = tid >> 6;
    const int m0 = blockIdx.y * BM;
    const int n0 = blockIdx.x * BN;
    const int wm = (wave >> 1) * 64;
    const int wn = (wave & 1) * 64;
    const int al = lane & 15;
    const int q  = lane >> 4;
    const int al7 = al & 7;

    // ---- staging descriptors: thread handles chunks c = tid + j*256,
    // row = c>>3, LDS slot p = c&7 holds global chunk g = p ^ (row&7).
    int t00[4], ww[4];
    const __hip_bfloat16* pBbase[4];
#pragma unroll
    for (int j = 0; j < 4; ++j) {
        const int c = tid + j * 256;
        const int row = c >> 3;
        const int g = (c & 7) ^ (row & 7);
        // A: merged row m0+row (clamped at the M edge; stores are guarded)
        int gm = m0 + row; if (gm > M_TOT - 1) gm = M_TOT - 1;
        int img = 0;
#pragma unroll
        for (int u = 1; u < 6; ++u) if (gm >= c_blkoff[u]) img = u;
        const int bi = gm - c_blkoff[img];
        const int wmrg = c_wm[img];
        const int gi = bi / wmrg;
        const int gj = bi - gi * wmrg;
        ww[j]  = c_w[img];
        t00[j] = c_tokoff[img] + 2 * gi * ww[j] + 2 * gj;   // token row of (kh,kw)=(0,0)
        // fold the swizzled chunk offset into t00-based pointer later (g*8 elts)
        t00[j] = t00[j];  // token index; pointer built per segment
        pBbase[j] = Wp + (size_t)(n0 + row) * K_DIM + g * 8;
        ww[j] |= (g << 16);                                  // pack g with w
    }

    f32x4 acc[4][4];
#pragma unroll
    for (int i = 0; i < 4; ++i)
#pragma unroll
        for (int j = 0; j < 4; ++j)
            acc[i][j] = (f32x4){0.f, 0.f, 0.f, 0.f};

#pragma unroll
    for (int seg = 0; seg < 4; ++seg) {
        const int kh = seg >> 1, kw = seg & 1;
        const __hip_bfloat16* pA[4];
        const __hip_bfloat16* pB[4];
#pragma unroll
        for (int j = 0; j < 4; ++j) {
            const int w = ww[j] & 0xffff;
            const int g = ww[j] >> 16;
            pA[j] = A + (size_t)(t00[j] + kh * w + kw) * N_DIM + g * 8;
            pB[j] = pBbase[j] + seg * 1024;
        }
        for (int k2 = 0; k2 < 1024; k2 += BK) {
#pragma unroll
            for (int j = 0; j < 4; ++j)
                __builtin_amdgcn_global_load_lds(
                    (const __attribute__((address_space(1))) void*)(pA[j] + k2),
                    (__attribute__((address_space(3))) void*)(lA + (tid + j * 256) * 8),
                    16, 0, 0);
#pragma unroll
            for (int j = 0; j < 4; ++j)
                __builtin_amdgcn_global_load_lds(
                    (const __attribute__((address_space(1))) void*)(pB[j] + k2),
                    (__attribute__((address_space(3))) void*)(lB + (tid + j * 256) * 8),
                    16, 0, 0);
            __syncthreads();   // DMA complete (vmcnt drain) before reads

            bf16x8 af[4], bfr[4];
#pragma unroll
            for (int ks = 0; ks < 2; ++ks) {
#pragma unroll
                for (int mi = 0; mi < 4; ++mi) {
                    const int r = wm + mi * 16 + al;
                    const int p = (ks * 4 + q) ^ al7;
                    af[mi] = *(const bf16x8*)(lA + r * BK + p * 8);
                }
#pragma unroll
                for (int ni = 0; ni < 4; ++ni) {
                    const int r = wn + ni * 16 + al;
                    const int p = (ks * 4 + q) ^ al7;
                    bfr[ni] = *(const bf16x8*)(lB + r * BK + p * 8);
                }
#pragma unroll
                for (int mi = 0; mi < 4; ++mi)
#pragma unroll
                    for (int ni = 0; ni < 4; ++ni)
                        acc[mi][ni] = __builtin_amdgcn_mfma_f32_16x16x32_bf16(
                            af[mi], bfr[ni], acc[mi][ni], 0, 0, 0);
            }
            __syncthreads();   // reads done before next tile's DMA lands
        }
    }

    // C/D layout: col = lane&15, row = (lane>>4)*4 + reg
#pragma unroll
    for (int mi = 0; mi < 4; ++mi) {
        const int row = m0 + wm + mi * 16 + q * 4;
#pragma unroll
        for (int ni = 0; ni < 4; ++ni) {
            const int col = n0 + wn + ni * 16 + al;
            float* cp = C + (size_t)row * N_DIM + col;
#pragma unroll
            for (int rg = 0; rg < 4; ++rg) {
                if (row + rg < M_TOT) cp[(size_t)rg * N_DIM] = acc[mi][ni][rg];
            }
        }
    }
}

extern "C" void kernel_launch(void* const* d_in, const int* in_sizes, int n_in,
                              void* d_out, int out_size, void* d_ws, size_t ws_size,
                              hipStream_t stream)
{
    const float* feat = (const float*)d_in[0];
    const float* wgt  = (const float*)d_in[1];
    float* out = (float*)d_out;

    __hip_bfloat16* featbf = (__hip_bfloat16*)d_ws;               // 98 MB
    __hip_bfloat16* wp = (__hip_bfloat16*)((char*)d_ws +
                         (size_t)47820 * N_DIM * sizeof(__hip_bfloat16)); // +8 MB

    cvt_feat<<<23910, 256, 0, stream>>>(feat, featbf);
    wperm_cvt<<<2048, 256, 0, stream>>>(wgt, wp);

    dim3 grid(N_DIM / BN, (M_TOT + BM - 1) / BM);  // (8, 94)
    gemm_bt<<<grid, 256, 0, stream>>>(featbf, wp, out);
}